// Round 1
// baseline (11923.314 us; speedup 1.0000x reference)
//
#include <hip/hip_runtime.h>

#define T_TOTAL 2048

typedef short bf16x8 __attribute__((ext_vector_type(8)));
typedef float f32x4 __attribute__((ext_vector_type(4)));

// workspace layout (bytes)
#define OFF_WT  0ull                      // W_t bf16 [2][1024][256]  (1 MiB)
#define OFF_UT  (1ull<<20)                // U_t bf16 [2][1024][256]  (1 MiB)
#define OFF_HST (2ull<<20)                // h state f32 [2][64][256] (128 KiB)
#define OFF_CST (OFF_HST + (128ull<<10))  // c state f32 [2][64][256]
#define OFF_XW  (3ull<<20)                // xw ring f32 [Tseg][2][4][1024][16]
#define STEP_BYTES 524288ull              // one step of xw (f32)

__device__ __forceinline__ unsigned short f2bf(float f){
  unsigned int u = __builtin_bit_cast(unsigned int, f);
  u += 0x7fffu + ((u>>16)&1u);
  return (unsigned short)(u>>16);
}
__device__ __forceinline__ float sigf(float z){ return 1.0f/(1.0f + __expf(-z)); }
__device__ __forceinline__ float tanhf_(float z){ return 2.0f/(1.0f + __expf(-2.0f*z)) - 1.0f; }

// ---------------- prep: transpose W,U to [dir][col][k] bf16 ----------------
__global__ __launch_bounds__(256) void kprep(const float* __restrict__ Wf, const float* __restrict__ Uf,
                                             const float* __restrict__ Wb, const float* __restrict__ Ub,
                                             unsigned short* __restrict__ ws){
  __shared__ float tile[64][65];
  int mat = blockIdx.z; // 0 Wf, 1 Wb, 2 Uf, 3 Ub
  const float* src = (mat==0)?Wf:(mat==1)?Wb:(mat==2)?Uf:Ub;
  unsigned short* dst = ws + ((mat<2)?0u:524288u) + (unsigned)(mat&1)*262144u;
  int c0 = blockIdx.x*64, k0 = blockIdx.y*64;
  int tx = threadIdx.x & 63, ty = threadIdx.x >> 6;
  #pragma unroll
  for (int j=0;j<16;j++){
    int r = j*4+ty;
    tile[r][tx] = src[(size_t)(k0+r)*1024 + (c0+tx)];
  }
  __syncthreads();
  #pragma unroll
  for (int j=0;j<16;j++){
    int r = j*4+ty;
    dst[(size_t)(c0+r)*256 + (k0+tx)] = f2bf(tile[tx][r]);
  }
}

// ---------------- xw GEMM: xw[s][dir][q][col][b16] = x[t_src]@W + bias -----
__global__ __launch_bounds__(512) void kgemm(const float* __restrict__ x,
        const float* __restrict__ biasF, const float* __restrict__ biasB,
        const unsigned short* __restrict__ wsu, float* __restrict__ xw, int s0){
  __shared__ __align__(16) char axs[32768]; // A slots: [q][ks][L][16B]
  int dir = blockIdx.y;
  int sg = s0 + blockIdx.x;
  int t_src = dir ? (T_TOTAL-1-sg) : sg;
  int tid = threadIdx.x, w = tid>>6, l = tid&63;
  int l15 = l&15, kq = l>>4;
  {
    int ks = l>>3, kqx = (l>>1)&3, e0 = (l&1)*4;
    #pragma unroll
    for (int i=0;i<8;i++){
      int b = w + 8*i;
      const float* px = x + ((size_t)b*T_TOTAL + t_src)*256 + 4*l;
      float4 v = *(const float4*)px;
      uint2 pk;
      pk.x = (unsigned)f2bf(v.x) | ((unsigned)f2bf(v.y)<<16);
      pk.y = (unsigned)f2bf(v.z) | ((unsigned)f2bf(v.w)<<16);
      *(uint2*)(axs + ((b>>4)*8192 + ks*1024 + ((b&15) + 16*kqx)*16 + e0*2)) = pk;
    }
  }
  __syncthreads();
  int q = w>>1, ch = w&1;
  const unsigned short* WT = wsu + (size_t)dir*262144u;
  const float* bias = dir ? biasB : biasF;
  f32x4 acc[32];
  #pragma unroll
  for (int ct=0;ct<32;ct++){
    float bv = bias[ch*512 + ct*16 + l15];
    acc[ct][0]=bv; acc[ct][1]=bv; acc[ct][2]=bv; acc[ct][3]=bv;
  }
  #pragma unroll
  for (int ks=0;ks<8;ks++){
    bf16x8 a = *(const bf16x8*)(axs + q*8192 + ks*1024 + l*16);
    #pragma unroll
    for (int ct=0;ct<32;ct++){
      const char* bp = (const char*)WT + (size_t)(ch*512 + ct*16 + l15)*512 + ks*64 + kq*16;
      bf16x8 b = *(const bf16x8*)bp;
      acc[ct] = __builtin_amdgcn_mfma_f32_16x16x32_bf16(a, b, acc[ct], 0, 0, 0);
    }
  }
  float* outp = xw + (size_t)blockIdx.x*131072u + (size_t)dir*65536u + (size_t)q*16384u;
  #pragma unroll
  for (int ct=0;ct<32;ct++){
    int col = ch*512 + ct*16 + l15;
    float4 v; v.x=acc[ct][0]; v.y=acc[ct][1]; v.z=acc[ct][2]; v.w=acc[ct][3];
    *(float4*)(outp + (size_t)col*16 + kq*4) = v;
  }
}

// ---------------- recurrent scan: 8 blocks = 2 dirs x 4 batch-quads --------
__global__ __launch_bounds__(512) void krec(const unsigned short* __restrict__ wsu,
        const float* __restrict__ xw, float* __restrict__ hst, float* __restrict__ cst,
        float* __restrict__ out, int nsteps, int first, int last){
  extern __shared__ char smem[];
  char* hsl = smem + 131072; // h slots: ks*1024 + L*16 (8 KiB)
  int bid = blockIdx.x;
  int dir = bid>>2, q = bid&3;
  int tid = threadIdx.x, w = tid>>6, l = tid&63;
  int l15 = l&15, kq = l>>4;
  const char* UT = (const char*)(wsu + 524288u + (size_t)dir*262144u);

  // resident U fragments: ks 0..3 in regs, ks 4..5 into LDS slots, ks 6..7 JIT
  bf16x8 ur[2][4][4];
  #pragma unroll
  for (int s=0;s<2;s++){
    #pragma unroll
    for (int g=0;g<4;g++){
      int col = g*256 + 32*w + 16*s + l15;
      const char* base = UT + (size_t)col*512 + kq*16;
      #pragma unroll
      for (int ks=0;ks<4;ks++) ur[s][g][ks] = *(const bf16x8*)(base + ks*64);
      #pragma unroll
      for (int k2=0;k2<2;k2++){
        bf16x8 t = *(const bf16x8*)(base + (4+k2)*64);
        *(bf16x8*)(smem + ((((w*2+s)*4+g)*2+k2)*1024 + l*16)) = t;
      }
    }
  }

  float c_[2][4];
  if (first){
    #pragma unroll
    for (int s=0;s<2;s++){
      #pragma unroll
      for (int r=0;r<4;r++) c_[s][r]=0.0f;
    }
    *(uint4*)(hsl + tid*16) = make_uint4(0u,0u,0u,0u);
  } else {
    #pragma unroll
    for (int s=0;s<2;s++){
      #pragma unroll
      for (int r=0;r<4;r++){
        int b = 4*kq + r, j = 32*w + 16*s + l15;
        size_t off = ((size_t)dir*64 + q*16 + b)*256 + j;
        float hv = hst[off];
        c_[s][r] = cst[off];
        int L = b + 16*((j>>3)&3);
        *(unsigned short*)(hsl + (j>>5)*1024 + L*16 + (j&7)*2) = f2bf(hv);
      }
    }
  }
  __syncthreads();

  const float* XW = xw + (size_t)dir*65536u + (size_t)q*16384u;
  float4 xpf[2][4];
  #pragma unroll
  for (int s=0;s<2;s++){
    #pragma unroll
    for (int g=0;g<4;g++){
      int col = g*256 + 32*w + 16*s + l15;
      xpf[s][g] = *(const float4*)(XW + (size_t)col*16 + kq*4);
    }
  }

  float hval[2][4];
  for (int t=0; t<nsteps; ++t){
    #pragma unroll
    for (int s=0;s<2;s++){
      f32x4 acc[4];
      #pragma unroll
      for (int g=0;g<4;g++){
        acc[g][0]=xpf[s][g].x; acc[g][1]=xpf[s][g].y; acc[g][2]=xpf[s][g].z; acc[g][3]=xpf[s][g].w;
      }
      bf16x8 jb[4][2];
      #pragma unroll
      for (int g=0;g<4;g++){
        int col = g*256 + 32*w + 16*s + l15;
        const char* base = UT + (size_t)col*512 + kq*16;
        jb[g][0] = *(const bf16x8*)(base + 6*64);
        jb[g][1] = *(const bf16x8*)(base + 7*64);
      }
      { // prefetch next step's xw half (consumed only next iteration)
        int tn = (t+1 < nsteps) ? (t+1) : t;
        #pragma unroll
        for (int g=0;g<4;g++){
          int col = g*256 + 32*w + 16*s + l15;
          xpf[s][g] = *(const float4*)(XW + (size_t)tn*131072u + (size_t)col*16 + kq*4);
        }
      }
      #pragma unroll
      for (int ks=0;ks<8;ks++){
        bf16x8 a = *(const bf16x8*)(hsl + ks*1024 + l*16);
        #pragma unroll
        for (int g=0;g<4;g++){
          bf16x8 b;
          if (ks<4)      b = ur[s][g][ks];
          else if (ks<6) b = *(const bf16x8*)(smem + ((((w*2+s)*4+g)*2+(ks-4))*1024 + l*16));
          else           b = jb[g][ks-6];
          acc[g] = __builtin_amdgcn_mfma_f32_16x16x32_bf16(a, b, acc[g], 0, 0, 0);
        }
      }
      #pragma unroll
      for (int r=0;r<4;r++){
        float ig = sigf(acc[0][r]);
        float fg = sigf(acc[1][r]);
        float gg = tanhf_(acc[2][r]);
        float og = sigf(acc[3][r]);
        float cn = fg*c_[s][r] + ig*gg;
        c_[s][r] = cn;
        hval[s][r] = og*tanhf_(cn);
      }
    }
    __syncthreads();   // all waves done reading h(t)
    if (t == nsteps-1){
      if (last){
        #pragma unroll
        for (int s=0;s<2;s++){
          #pragma unroll
          for (int r=0;r<4;r++){
            int b = q*16 + 4*kq + r, j = 32*w + 16*s + l15;
            out[(size_t)b*512 + dir*256 + j] = hval[s][r];
          }
        }
      } else {
        #pragma unroll
        for (int s=0;s<2;s++){
          #pragma unroll
          for (int r=0;r<4;r++){
            int b = 4*kq + r, j = 32*w + 16*s + l15;
            size_t off = ((size_t)dir*64 + q*16 + b)*256 + j;
            hst[off] = hval[s][r];
            cst[off] = c_[s][r];
          }
        }
      }
    } else {
      #pragma unroll
      for (int s=0;s<2;s++){
        #pragma unroll
        for (int r=0;r<4;r++){
          int b = 4*kq + r, j = 32*w + 16*s + l15;
          int L = b + 16*((j>>3)&3);
          *(unsigned short*)(hsl + (j>>5)*1024 + L*16 + (j&7)*2) = f2bf(hval[s][r]);
        }
      }
    }
    __syncthreads();   // h(t+1) visible
  }
}

extern "C" void kernel_launch(void* const* d_in, const int* in_sizes, int n_in,
                              void* d_out, int out_size, void* d_ws, size_t ws_size,
                              hipStream_t stream){
  (void)in_sizes; (void)n_in; (void)out_size;
  const float* x   = (const float*)d_in[0];
  const float* Wf  = (const float*)d_in[1];
  const float* Uf  = (const float*)d_in[2];
  const float* bf_ = (const float*)d_in[3];
  const float* Wb  = (const float*)d_in[4];
  const float* Ub  = (const float*)d_in[5];
  const float* bb  = (const float*)d_in[6];
  float* out = (float*)d_out;
  char* ws = (char*)d_ws;
  unsigned short* wsu = (unsigned short*)ws;
  float* hst = (float*)(ws + OFF_HST);
  float* cst = (float*)(ws + OFF_CST);
  float* xwb = (float*)(ws + OFF_XW);

  hipFuncSetAttribute((const void*)krec, hipFuncAttributeMaxDynamicSharedMemorySize, 139264);

  kprep<<<dim3(16,4,4), 256, 0, stream>>>(Wf, Uf, Wb, Ub, wsu);

  long long avail = (long long)ws_size - (long long)OFF_XW;
  int Tseg = (avail > 0) ? (int)(avail / (long long)STEP_BYTES) : 1;
  if (Tseg < 1) Tseg = 1;
  if (Tseg > T_TOTAL) Tseg = T_TOTAL;
  int nseg = (T_TOTAL + Tseg - 1)/Tseg;
  int s0 = 0;
  for (int seg=0; seg<nseg; ++seg){
    int Tthis = (T_TOTAL - s0 < Tseg) ? (T_TOTAL - s0) : Tseg;
    kgemm<<<dim3(Tthis,2), 512, 0, stream>>>(x, bf_, bb, wsu, xwb, s0);
    krec<<<dim3(8), 512, 139264, stream>>>(wsu, xwb, hst, cst, out, Tthis,
                                           (seg==0)?1:0, (seg==nseg-1)?1:0);
    s0 += Tthis;
  }
}

// Round 2
// 9768.105 us; speedup vs baseline: 1.2206x; 1.2206x over previous
//
#include <hip/hip_runtime.h>

#define T_TOTAL 2048

typedef short bf16x8 __attribute__((ext_vector_type(8)));
typedef float f32x4 __attribute__((ext_vector_type(4)));

// workspace layout (bytes)
#define OFF_WT  0ull                      // W_t bf16 [2][1024 col][256 k]      (1 MiB)
#define OFF_UT  (1ull<<20)                // U slots bf16 [2][512 slot][64][16B](1 MiB)
#define OFF_HST (2ull<<20)                // h state f32 [2][64][256] (64 KiB used)
#define OFF_CST (OFF_HST + (128ull<<10))  // c state f32 [2][64][256]
#define OFF_XW  (3ull<<20)                // xw ring bf16 [Tseg][2][4][1024][16]
#define STEP_BYTES 262144ull              // one step of xw (bf16)

__device__ __forceinline__ unsigned short f2bf(float f){
  unsigned int u = __builtin_bit_cast(unsigned int, f);
  u += 0x7fffu + ((u>>16)&1u);
  return (unsigned short)(u>>16);
}
__device__ __forceinline__ float bfhi2f(unsigned int u){ // upper 16 bits are the bf16
  unsigned int v = u & 0xffff0000u; return __builtin_bit_cast(float, v);
}
__device__ __forceinline__ float bflo2f(unsigned int u){
  unsigned int v = u << 16; return __builtin_bit_cast(float, v);
}
__device__ __forceinline__ float sigf(float z){ return 1.0f/(1.0f + __expf(-z)); }
__device__ __forceinline__ float tanhf_(float z){ return 2.0f/(1.0f + __expf(-2.0f*z)) - 1.0f; }

// ---------------- prep: W -> [dir][col][k] bf16 ; U -> fragment slots ------
__global__ __launch_bounds__(256) void kprep(const float* __restrict__ Wf, const float* __restrict__ Uf,
                                             const float* __restrict__ Wb, const float* __restrict__ Ub,
                                             unsigned short* __restrict__ ws){
  __shared__ float tile[64][65];
  int mat = blockIdx.z; // 0 Wf, 1 Wb, 2 Uf, 3 Ub
  const float* src = (mat==0)?Wf:(mat==1)?Wb:(mat==2)?Uf:Ub;
  int c0 = blockIdx.x*64, k0 = blockIdx.y*64;
  int tx = threadIdx.x & 63, ty = threadIdx.x >> 6;
  #pragma unroll
  for (int j=0;j<16;j++){
    int r = j*4+ty;
    tile[r][tx] = src[(size_t)(k0+r)*1024 + (c0+tx)];
  }
  __syncthreads();
  if (mat < 2){
    unsigned short* dst = ws + (unsigned)mat*262144u;
    #pragma unroll
    for (int j=0;j<16;j++){
      int r = j*4+ty;
      dst[(size_t)(c0+r)*256 + (k0+tx)] = f2bf(tile[tx][r]);
    }
  } else {
    unsigned short* dst = ws + 524288u + (unsigned)(mat&1)*262144u;
    #pragma unroll
    for (int j=0;j<16;j++){
      int r = j*4+ty;
      int col = c0+r, k = k0+tx;
      int cg = col>>4, ks = k>>5, kq = (k>>3)&3, e = k&7;
      dst[(size_t)(cg*8+ks)*512 + ((col&15)+16*kq)*8 + e] = f2bf(tile[tx][r]);
    }
  }
}

// ---------------- xw GEMM: xw[s][dir][q][col][b16] (bf16) = x@W + bias -----
__global__ __launch_bounds__(512, 2) void kgemm(const float* __restrict__ x,
        const float* __restrict__ biasF, const float* __restrict__ biasB,
        const unsigned short* __restrict__ wsu, char* __restrict__ xw, int s0){
  __shared__ __align__(16) char axs[32768]; // A slots: [q][ks][L][16B]
  int dir = blockIdx.y;
  int sg = s0 + blockIdx.x;
  int t_src = dir ? (T_TOTAL-1-sg) : sg;
  int tid = threadIdx.x, w = tid>>6, l = tid&63;
  int l15 = l&15, kq = l>>4;
  {
    int ks = l>>3, kqx = (l>>1)&3, e0 = (l&1)*4;
    #pragma unroll
    for (int i=0;i<8;i++){
      int b = w + 8*i;
      const float* px = x + ((size_t)b*T_TOTAL + t_src)*256 + 4*l;
      float4 v = *(const float4*)px;
      uint2 pk;
      pk.x = (unsigned)f2bf(v.x) | ((unsigned)f2bf(v.y)<<16);
      pk.y = (unsigned)f2bf(v.z) | ((unsigned)f2bf(v.w)<<16);
      *(uint2*)(axs + ((b>>4)*8192 + ks*1024 + ((b&15) + 16*kqx)*16 + e0*2)) = pk;
    }
  }
  __syncthreads();
  int q = w>>1, ch = w&1;
  const unsigned short* WT = wsu + (size_t)dir*262144u;
  const float* bias = dir ? biasB : biasF;
  f32x4 acc[32];
  #pragma unroll
  for (int ct=0;ct<32;ct++){
    float bv = bias[ch*512 + ct*16 + l15];
    acc[ct][0]=bv; acc[ct][1]=bv; acc[ct][2]=bv; acc[ct][3]=bv;
  }
  #pragma unroll
  for (int ks=0;ks<8;ks++){
    bf16x8 a = *(const bf16x8*)(axs + q*8192 + ks*1024 + l*16);
    #pragma unroll
    for (int ct=0;ct<32;ct++){
      const char* bp = (const char*)WT + (size_t)(ch*512 + ct*16 + l15)*512 + ks*64 + kq*16;
      bf16x8 b = *(const bf16x8*)bp;
      acc[ct] = __builtin_amdgcn_mfma_f32_16x16x32_bf16(a, b, acc[ct], 0, 0, 0);
    }
  }
  char* outp = xw + (size_t)blockIdx.x*STEP_BYTES + (size_t)dir*131072u + (size_t)q*32768u;
  #pragma unroll
  for (int ct=0;ct<32;ct++){
    int col = ch*512 + ct*16 + l15;
    uint2 pk;
    pk.x = (unsigned)f2bf(acc[ct][0]) | ((unsigned)f2bf(acc[ct][1])<<16);
    pk.y = (unsigned)f2bf(acc[ct][2]) | ((unsigned)f2bf(acc[ct][3])<<16);
    *(uint2*)(outp + (size_t)col*32 + kq*8) = pk;
  }
}

// ---------------- recurrent scan: 8 blocks = 2 dirs x 4 batch-quads --------
__global__ __launch_bounds__(512, 2) void krec(const unsigned short* __restrict__ wsu,
        const char* __restrict__ xw, float* __restrict__ hst, float* __restrict__ cst,
        float* __restrict__ out, int nsteps, int first, int last){
  extern __shared__ char smem[];
  char* hsl = smem + 131072; // h slots: ks*1024 + L*16 (8 KiB)
  int bid = blockIdx.x;
  int dir = bid>>2, q = bid&3;
  int tid = threadIdx.x, w = tid>>6, l = tid&63;
  int l15 = l&15, kq = l>>4;
  const char* UT = (const char*)(wsu + 524288u + (size_t)dir*262144u);

  // U residency: slot index (cg*8 + ks), cg = g*16 + 2*w + s, lane offset l*16.
  // ks 0..3 in regs (128 VGPR), ks 4..5 in LDS (128 KiB), ks 6..7 JIT from L2.
  bf16x8 ur[2][4][4];
  #pragma unroll
  for (int s=0;s<2;s++){
    #pragma unroll
    for (int g=0;g<4;g++){
      int cg = g*16 + 2*w + s;
      const char* base = UT + (size_t)cg*8192 + (size_t)l*16;
      #pragma unroll
      for (int ks=0;ks<4;ks++) ur[s][g][ks] = *(const bf16x8*)(base + ks*1024);
      #pragma unroll
      for (int k2=0;k2<2;k2++){
        bf16x8 t = *(const bf16x8*)(base + (4+k2)*1024);
        *(bf16x8*)(smem + ((((w*2+s)*4+g)*2+k2)*1024 + l*16)) = t;
      }
    }
  }

  float c_[2][4];
  if (first){
    #pragma unroll
    for (int s=0;s<2;s++){
      #pragma unroll
      for (int r=0;r<4;r++) c_[s][r]=0.0f;
    }
    *(uint4*)(hsl + tid*16) = make_uint4(0u,0u,0u,0u);
  } else {
    #pragma unroll
    for (int s=0;s<2;s++){
      #pragma unroll
      for (int r=0;r<4;r++){
        int b = 4*kq + r, j = 32*w + 16*s + l15;
        size_t off = ((size_t)dir*64 + q*16 + b)*256 + j;
        float hv = hst[off];
        c_[s][r] = cst[off];
        int L = b + 16*((j>>3)&3);
        *(unsigned short*)(hsl + (j>>5)*1024 + L*16 + (j&7)*2) = f2bf(hv);
      }
    }
  }
  __syncthreads();

  const char* XW = xw + (size_t)dir*131072u + (size_t)q*32768u;
  uint2 xpf[2][4];
  #pragma unroll
  for (int s=0;s<2;s++){
    #pragma unroll
    for (int g=0;g<4;g++){
      int col = g*256 + 32*w + 16*s + l15;
      xpf[s][g] = *(const uint2*)(XW + (size_t)col*32 + kq*8);
    }
  }

  float hval[2][4];
  for (int t=0; t<nsteps; ++t){
    #pragma unroll
    for (int s=0;s<2;s++){
      f32x4 acc[4];
      #pragma unroll
      for (int g=0;g<4;g++){
        uint2 v = xpf[s][g];
        acc[g][0]=bflo2f(v.x); acc[g][1]=bfhi2f(v.x);
        acc[g][2]=bflo2f(v.y); acc[g][3]=bfhi2f(v.y);
      }
      { // prefetch next step's xw half (consumed only next iteration)
        int tn = (t+1 < nsteps) ? (t+1) : t;
        #pragma unroll
        for (int g=0;g<4;g++){
          int col = g*256 + 32*w + 16*s + l15;
          xpf[s][g] = *(const uint2*)(XW + (size_t)tn*STEP_BYTES + (size_t)col*32 + kq*8);
        }
      }
      bf16x8 jb[4][2];
      #pragma unroll
      for (int g=0;g<4;g++){
        int cg = g*16 + 2*w + s;
        const char* base = UT + (size_t)cg*8192 + (size_t)l*16;
        jb[g][0] = *(const bf16x8*)(base + 6*1024);
        jb[g][1] = *(const bf16x8*)(base + 7*1024);
      }
      #pragma unroll
      for (int ks=0;ks<8;ks++){
        bf16x8 a = *(const bf16x8*)(hsl + ks*1024 + l*16);
        #pragma unroll
        for (int g=0;g<4;g++){
          bf16x8 b;
          if (ks<4)      b = ur[s][g][ks];
          else if (ks<6) b = *(const bf16x8*)(smem + ((((w*2+s)*4+g)*2+(ks-4))*1024 + l*16));
          else           b = jb[g][ks-6];
          acc[g] = __builtin_amdgcn_mfma_f32_16x16x32_bf16(a, b, acc[g], 0, 0, 0);
        }
      }
      #pragma unroll
      for (int r=0;r<4;r++){
        float ig = sigf(acc[0][r]);
        float fg = sigf(acc[1][r]);
        float gg = tanhf_(acc[2][r]);
        float og = sigf(acc[3][r]);
        float cn = fg*c_[s][r] + ig*gg;
        c_[s][r] = cn;
        hval[s][r] = og*tanhf_(cn);
      }
    }
    __syncthreads();   // all waves done reading h(t)
    if (t == nsteps-1){
      if (last){
        #pragma unroll
        for (int s=0;s<2;s++){
          #pragma unroll
          for (int r=0;r<4;r++){
            int b = q*16 + 4*kq + r, j = 32*w + 16*s + l15;
            out[(size_t)b*512 + dir*256 + j] = hval[s][r];
          }
        }
      } else {
        #pragma unroll
        for (int s=0;s<2;s++){
          #pragma unroll
          for (int r=0;r<4;r++){
            int b = 4*kq + r, j = 32*w + 16*s + l15;
            size_t off = ((size_t)dir*64 + q*16 + b)*256 + j;
            hst[off] = hval[s][r];
            cst[off] = c_[s][r];
          }
        }
      }
    } else {
      #pragma unroll
      for (int s=0;s<2;s++){
        #pragma unroll
        for (int r=0;r<4;r++){
          int b = 4*kq + r, j = 32*w + 16*s + l15;
          int L = b + 16*((j>>3)&3);
          *(unsigned short*)(hsl + (j>>5)*1024 + L*16 + (j&7)*2) = f2bf(hval[s][r]);
        }
      }
    }
    __syncthreads();   // h(t+1) visible
  }
}

extern "C" void kernel_launch(void* const* d_in, const int* in_sizes, int n_in,
                              void* d_out, int out_size, void* d_ws, size_t ws_size,
                              hipStream_t stream){
  (void)in_sizes; (void)n_in; (void)out_size;
  const float* x   = (const float*)d_in[0];
  const float* Wf  = (const float*)d_in[1];
  const float* Uf  = (const float*)d_in[2];
  const float* bf_ = (const float*)d_in[3];
  const float* Wb  = (const float*)d_in[4];
  const float* Ub  = (const float*)d_in[5];
  const float* bb  = (const float*)d_in[6];
  float* out = (float*)d_out;
  char* ws = (char*)d_ws;
  unsigned short* wsu = (unsigned short*)ws;
  float* hst = (float*)(ws + OFF_HST);
  float* cst = (float*)(ws + OFF_CST);
  char* xwb = ws + OFF_XW;

  hipFuncSetAttribute((const void*)krec, hipFuncAttributeMaxDynamicSharedMemorySize, 139264);

  kprep<<<dim3(16,4,4), 256, 0, stream>>>(Wf, Uf, Wb, Ub, wsu);

  long long avail = (long long)ws_size - (long long)OFF_XW;
  int Tseg = (avail > 0) ? (int)(avail / (long long)STEP_BYTES) : 1;
  if (Tseg < 1) Tseg = 1;
  if (Tseg > T_TOTAL) Tseg = T_TOTAL;
  int nseg = (T_TOTAL + Tseg - 1)/Tseg;
  int s0 = 0;
  for (int seg=0; seg<nseg; ++seg){
    int Tthis = (T_TOTAL - s0 < Tseg) ? (T_TOTAL - s0) : Tseg;
    kgemm<<<dim3(Tthis,2), 512, 0, stream>>>(x, bf_, bb, wsu, xwb, s0);
    krec<<<dim3(8), 512, 139264, stream>>>(wsu, xwb, hst, cst, out, Tthis,
                                           (seg==0)?1:0, (seg==nseg-1)?1:0);
    s0 += Tthis;
  }
}